// Round 10
// baseline (31.325 us; speedup 1.0000x reference)
//
#include <hip/hip_runtime.h>
#include <hip/hip_bf16.h>
#include <math.h>

#define NODES 128
#define KMIX  8
#define NSAMP 4096
#define STOT  8192            // X and noise stacked
#define ZPAIR 8128            // 128*127/2
#define FDIM  256             // [cos | sin] feature dim

using bf16x8 = __attribute__((ext_vector_type(8))) short;
using f32x4  = __attribute__((ext_vector_type(4))) float;

// ---------------- ws layout (in float slots) ----------------
#define OF_F   ((size_t)0)                          // bf16 F[8192][256]
#define OF_M   (OF_F + (size_t)STOT * FDIM / 2)     // bf16 W[8][256][256]
#define OF_LP4 (OF_M + (size_t)KMIX * FDIM * FDIM / 2)  // f32 [2][8][8192]
#define OF_PT  (OF_LP4 + (size_t)4 * KMIX * STOT)   // f32 [32] partials
#define OF_CT  (OF_PT + 32)                         // u32 [1] ticket counter

__device__ __forceinline__ float bf2f(short u) {
    union { unsigned u32; float f; } cv;
    cv.u32 = ((unsigned)(unsigned short)u) << 16;
    return cv.f;
}
__device__ __forceinline__ short f2bf(float f) {
    union { float f; unsigned u32; } cv; cv.f = f;
    unsigned r = cv.u32 + 0x7fff + ((cv.u32 >> 16) & 1);   // round-nearest-even
    return (short)(r >> 16);
}
__device__ __forceinline__ float softplusf(float x) {
    return fmaxf(x, 0.0f) + log1pf(expf(-fabsf(x)));
}

// ---------------------------------------------------------------------------
// prep (launch-fused, bodies r7-verbatim): blocks [0,4096): sincos features
//                                          blocks [4096,6144): build W
// W = [[S0/2, 0],[K1, S0/2]]
// ---------------------------------------------------------------------------
#define FEAT_BLOCKS (STOT * NODES / 256)            // 4096
#define WB_BLOCKS   (KMIX * FDIM * FDIM / 256)      // 2048

__global__ void prep_kernel(const float* __restrict__ X, const float* __restrict__ noise,
                            const float* __restrict__ theta,
                            short* __restrict__ F, short* __restrict__ W) {
    const int b = blockIdx.x, t = threadIdx.x;
    if (b < FEAT_BLOCKS) {
        int idx = b * 256 + t;                      // 0 .. STOT*NODES-1
        int s = idx >> 7, i = idx & 127;
        float v = (s < NSAMP) ? X[idx] : noise[idx - NSAMP * NODES];
        float sv, cv;
        __sincosf(v, &sv, &cv);
        F[(size_t)s * FDIM + i]       = f2bf(cv);
        F[(size_t)s * FDIM + 128 + i] = f2bf(sv);
    } else {
        int idx = (b - FEAT_BLOCKS) * 256 + t;      // 0 .. KMIX*256*256-1
        int j = idx & 255, i = (idx >> 8) & 255, k = idx >> 16;
        int a = i & 127, bb = j & 127;
        int hi = i >> 7, hj = j >> 7;
        float val = 0.0f;
        if (a != bb) {
            int p = a < bb ? a : bb;
            int q = a < bb ? bb : a;
            int z = p * 127 - (p * (p - 1)) / 2 + (q - p - 1);
            if (hi == hj) {
                val = 0.5f * theta[(size_t)(k * 2 + 0) * ZPAIR + z];
            } else if (hi == 1 && hj == 0) {
                float t1 = theta[(size_t)(k * 2 + 1) * ZPAIR + z];
                val = (a < bb) ? t1 : -t1;
            }
        }
        W[idx] = f2bf(val);
    }
}

// ---------------------------------------------------------------------------
// combined GEMM (r9-verbatim): one block per (k, s-tile), both i-halves.
// ---------------------------------------------------------------------------
__global__ __launch_bounds__(256, 2) void gemm_fused(
        const short* __restrict__ F, const short* __restrict__ M,
        float* __restrict__ lp2) {
    __shared__ short Ft[2][128 * 64];
    __shared__ short Mt[2][128 * 64];

    const int bid = blockIdx.x;
    const int k   = bid >> 6;          // 8 k x 64 s-tiles
    const int st  = bid & 63;
    const int sbase = st * 128;

    const int t = threadIdx.x;
    const int wid = t >> 6, lane = t & 63;
    const int wm = wid >> 1, wn = wid & 1;

    const short* Mk = M + (size_t)k * FDIM * FDIM;

    const int rg = lane >> 3;          // row within 8-row group (row&7 == rg)
    const int sc = (lane & 7) ^ rg;    // pre-swizzled source 16B-column

    f32x4 acc0[4][4] = {};             // P over i in [0,128)
    f32x4 acc1[4][4] = {};             // P over i in [128,256)

    auto stageF = [&](int buf, int c) {
        #pragma unroll
        for (int q = 0; q < 4; q++) {
            int g = wid * 4 + q;
            const short* src = F + ((size_t)(sbase + g * 8 + rg)) * FDIM + c * 64 + sc * 8;
            __builtin_amdgcn_global_load_lds((const unsigned*)src,
                                             (unsigned*)&Ft[buf][g * 512], 16, 0, 0);
        }
    };
    auto stageW = [&](int buf, int ihrow, int c) {
        #pragma unroll
        for (int q = 0; q < 4; q++) {
            int g = wid * 4 + q;
            const short* src = Mk + ((size_t)(ihrow * 128 + g * 8 + rg)) * FDIM + c * 64 + sc * 8;
            __builtin_amdgcn_global_load_lds((const unsigned*)src,
                                             (unsigned*)&Mt[buf][g * 512], 16, 0, 0);
        }
    };

    const int rlow = lane & 15, kq = lane >> 4;

    auto compute = [&](int fbuf, int mbuf, f32x4 (&acc)[4][4]) {
        bf16x8 afr[4][2], bfr[4][2];
        #pragma unroll
        for (int m = 0; m < 4; m++) {
            int row = wm * 64 + m * 16 + rlow;
            #pragma unroll
            for (int kk = 0; kk < 2; kk++) {
                int c16 = (kk * 4 + kq) ^ (row & 7);
                afr[m][kk] = *(const bf16x8*)&Ft[fbuf][row * 64 + c16 * 8];
            }
        }
        #pragma unroll
        for (int n = 0; n < 4; n++) {
            int row = wn * 64 + n * 16 + rlow;
            #pragma unroll
            for (int kk = 0; kk < 2; kk++) {
                int c16 = (kk * 4 + kq) ^ (row & 7);
                bfr[n][kk] = *(const bf16x8*)&Mt[mbuf][row * 64 + c16 * 8];
            }
        }
        #pragma unroll
        for (int m = 0; m < 4; m++)
            #pragma unroll
            for (int n = 0; n < 4; n++)
                #pragma unroll
                for (int kk = 0; kk < 2; kk++)
                    acc[m][n] = __builtin_amdgcn_mfma_f32_16x16x32_bf16(
                        afr[m][kk], bfr[n][kk], acc[m][n], 0, 0, 0);
    };

    // steps: s0(ih0,c0,F0,M0) s1(ih1,c0,F0,M1) s2(ih0,c1,F1,M0)
    //        s3(ih1,c1,F1,M1) s4(ih1,c2,F0,M0) s5(ih1,c3,F1,M1)
    stageF(0, 0); stageW(0, 0, 0);
    stageW(1, 1, 0);                   // step1 W
    __syncthreads();
    compute(0, 0, acc0);               // step0
    __syncthreads();
    stageF(1, 1); stageW(0, 0, 1);     // step2 operands
    __syncthreads();
    compute(0, 1, acc1);               // step1
    __syncthreads();
    stageW(1, 1, 1);                   // step3 W
    __syncthreads();
    compute(1, 0, acc0);               // step2
    __syncthreads();
    stageF(0, 2); stageW(0, 1, 2);     // step4 operands (Ft0 free: last read step1)
    __syncthreads();
    compute(1, 1, acc1);               // step3
    __syncthreads();
    stageF(1, 3); stageW(1, 1, 3);     // step5 operands (Ft1/Mt1 free: last read step3)
    __syncthreads();
    compute(0, 0, acc1);               // step4
    __syncthreads();
    compute(1, 1, acc1);               // step5

    // ---- epilogue: psum[s] = sum over BOTH i-halves of F[s,i]*P[s,i]
    float psum[4][4];
    #pragma unroll
    for (int m = 0; m < 4; m++) {
        #pragma unroll
        for (int q = 0; q < 4; q++) {
            int srow = wm * 64 + m * 16 + kq * 4 + q;
            const short* fr0 = F + (size_t)(sbase + srow) * FDIM + wn * 64 + rlow;
            float p = 0.0f;
            #pragma unroll
            for (int n = 0; n < 4; n++)
                p += bf2f(fr0[n * 16]) * acc0[m][n][q];
            #pragma unroll
            for (int n = 0; n < 4; n++)
                p += bf2f(fr0[128 + n * 16]) * acc1[m][n][q];
            psum[m][q] = p;
        }
    }
    #pragma unroll
    for (int off = 1; off < 16; off <<= 1)
        #pragma unroll
        for (int m = 0; m < 4; m++)
            #pragma unroll
            for (int q = 0; q < 4; q++)
                psum[m][q] += __shfl_xor(psum[m][q], off, 64);

    if (rlow == 0) {
        #pragma unroll
        for (int m = 0; m < 4; m++)
            #pragma unroll
            for (int q = 0; q < 4; q++) {
                int srow = wm * 64 + m * 16 + kq * 4 + q;
                lp2[((size_t)wn * KMIX + k) * STOT + sbase + srow] = psum[m][q];
            }
    }
}

// ---------------------------------------------------------------------------
// reduce: logsumexp + softplus + block partials; LAST block (device-scope
// ticket) sums the 32 partials in fixed order and writes J. final_kernel gone.
// ---------------------------------------------------------------------------
__global__ void reduce_kernel(const float* __restrict__ lp2,
                              const float* __restrict__ logc,
                              float* __restrict__ partials,
                              unsigned* __restrict__ counter,
                              float* __restrict__ out) {
    const int t = threadIdx.x;
    const int s = blockIdx.x * 256 + t;

    float v[KMIX];
    #pragma unroll
    for (int k = 0; k < KMIX; k++) {
        v[k] = lp2[((size_t)0 * KMIX + k) * STOT + s]
             + lp2[((size_t)1 * KMIX + k) * STOT + s]
             + logc[k];
    }
    float mx = v[0];
    #pragma unroll
    for (int k = 1; k < KMIX; k++) mx = fmaxf(mx, v[k]);
    float sum = 0.0f;
    #pragma unroll
    for (int k = 0; k < KMIX; k++) sum += expf(v[k] - mx);
    const float lp = mx + logf(sum);

    // n == m -> term1 = -softplus(-lp_data), term2 = -softplus(lp_noise)
    const float term = (s < NSAMP) ? -softplusf(-lp) : -softplusf(lp);

    float bsum = term;
    #pragma unroll
    for (int off = 32; off; off >>= 1) bsum += __shfl_down(bsum, off);
    __shared__ float wsum[4];
    if ((t & 63) == 0) wsum[t >> 6] = bsum;
    __syncthreads();

    if (t == 0) {
        partials[blockIdx.x] = wsum[0] + wsum[1] + wsum[2] + wsum[3];
        __threadfence();                              // release partial
        unsigned old = atomicAdd(counter, 1u);        // device-scope ticket
        if (old == 31u) {                             // last block: finalize
            __threadfence();                          // acquire all partials
            float tot = 0.0f;
            #pragma unroll
            for (int b = 0; b < 32; b++) tot += partials[b];
            out[0] = tot * (1.0f / (float)NSAMP);
        }
    }
}

// ---------------------------------------------------------------------------
extern "C" void kernel_launch(void* const* d_in, const int* in_sizes, int n_in,
                              void* d_out, int out_size, void* d_ws, size_t ws_size,
                              hipStream_t stream) {
    (void)in_sizes; (void)n_in; (void)out_size; (void)ws_size;
    const float* X     = (const float*)d_in[0];
    const float* noise = (const float*)d_in[1];
    const float* theta = (const float*)d_in[2];
    const float* logc  = (const float*)d_in[3];
    float* out = (float*)d_out;
    float* ws  = (float*)d_ws;

    short*    Fb    = (short*)(ws + OF_F);
    short*    Wb    = (short*)(ws + OF_M);
    float*    lp2   = ws + OF_LP4;
    float*    parts = ws + OF_PT;
    unsigned* ctr   = (unsigned*)(ws + OF_CT);

    hipMemsetAsync(ctr, 0, sizeof(unsigned), stream);     // zero ticket each call
    prep_kernel<<<FEAT_BLOCKS + WB_BLOCKS, 256, 0, stream>>>(X, noise, theta, Fb, Wb);
    gemm_fused<<<KMIX * (STOT / 128), 256, 0, stream>>>(Fb, Wb, lp2);
    reduce_kernel<<<STOT / 256, 256, 0, stream>>>(lp2, logc, parts, ctr, out);
}

// Round 11
// 26.707 us; speedup vs baseline: 1.1729x; 1.1729x over previous
//
#include <hip/hip_runtime.h>
#include <hip/hip_bf16.h>
#include <math.h>

#define NODES 128
#define KMIX  8
#define NSAMP 4096
#define STOT  8192            // X and noise stacked
#define ZPAIR 8128            // 128*127/2
#define FDIM  256             // [cos | sin] feature dim

using bf16x8 = __attribute__((ext_vector_type(8))) short;
using f32x4  = __attribute__((ext_vector_type(4))) float;

// ---------------- ws layout (in float slots) ----------------
#define OF_F   ((size_t)0)                          // bf16 F[8192][256]
#define OF_M   (OF_F + (size_t)STOT * FDIM / 2)     // bf16 W[8][256][256]
#define OF_LP4 (OF_M + (size_t)KMIX * FDIM * FDIM / 2)  // f32 [2][8][8192]
#define OF_PT  (OF_LP4 + (size_t)4 * KMIX * STOT)   // f32 [32] partials
#define OF_CT  (OF_PT + 32)                         // u32 [1] ticket counter

__device__ __forceinline__ float bf2f(short u) {
    union { unsigned u32; float f; } cv;
    cv.u32 = ((unsigned)(unsigned short)u) << 16;
    return cv.f;
}
__device__ __forceinline__ short f2bf(float f) {
    union { float f; unsigned u32; } cv; cv.f = f;
    unsigned r = cv.u32 + 0x7fff + ((cv.u32 >> 16) & 1);   // round-nearest-even
    return (short)(r >> 16);
}
__device__ __forceinline__ float softplusf(float x) {
    return fmaxf(x, 0.0f) + log1pf(expf(-fabsf(x)));
}

// ---------------------------------------------------------------------------
// prep (launch-fused): blocks [0,4096): sincos features
//                      blocks [4096,6144): build W
// Also zeroes the reduce ticket counter (replaces the costly memset node;
// kernel-boundary ordering makes it visible before reduce's atomics).
// W = [[S0/2, 0],[K1, S0/2]]
// ---------------------------------------------------------------------------
#define FEAT_BLOCKS (STOT * NODES / 256)            // 4096
#define WB_BLOCKS   (KMIX * FDIM * FDIM / 256)      // 2048

__global__ void prep_kernel(const float* __restrict__ X, const float* __restrict__ noise,
                            const float* __restrict__ theta,
                            short* __restrict__ F, short* __restrict__ W,
                            unsigned* __restrict__ ctr) {
    const int b = blockIdx.x, t = threadIdx.x;
    if (b == 0 && t == 0) *ctr = 0u;                // zero ticket (no memset node)
    if (b < FEAT_BLOCKS) {
        int idx = b * 256 + t;                      // 0 .. STOT*NODES-1
        int s = idx >> 7, i = idx & 127;
        float v = (s < NSAMP) ? X[idx] : noise[idx - NSAMP * NODES];
        float sv, cv;
        __sincosf(v, &sv, &cv);
        F[(size_t)s * FDIM + i]       = f2bf(cv);
        F[(size_t)s * FDIM + 128 + i] = f2bf(sv);
    } else {
        int idx = (b - FEAT_BLOCKS) * 256 + t;      // 0 .. KMIX*256*256-1
        int j = idx & 255, i = (idx >> 8) & 255, k = idx >> 16;
        int a = i & 127, bb = j & 127;
        int hi = i >> 7, hj = j >> 7;
        float val = 0.0f;
        if (a != bb) {
            int p = a < bb ? a : bb;
            int q = a < bb ? bb : a;
            int z = p * 127 - (p * (p - 1)) / 2 + (q - p - 1);
            if (hi == hj) {
                val = 0.5f * theta[(size_t)(k * 2 + 0) * ZPAIR + z];
            } else if (hi == 1 && hj == 0) {
                float t1 = theta[(size_t)(k * 2 + 1) * ZPAIR + z];
                val = (a < bb) ? t1 : -t1;
            }
        }
        W[idx] = f2bf(val);
    }
}

// ---------------------------------------------------------------------------
// combined GEMM (r9/r10-verbatim): one block per (k, s-tile), both i-halves.
// ---------------------------------------------------------------------------
__global__ __launch_bounds__(256, 2) void gemm_fused(
        const short* __restrict__ F, const short* __restrict__ M,
        float* __restrict__ lp2) {
    __shared__ short Ft[2][128 * 64];
    __shared__ short Mt[2][128 * 64];

    const int bid = blockIdx.x;
    const int k   = bid >> 6;          // 8 k x 64 s-tiles
    const int st  = bid & 63;
    const int sbase = st * 128;

    const int t = threadIdx.x;
    const int wid = t >> 6, lane = t & 63;
    const int wm = wid >> 1, wn = wid & 1;

    const short* Mk = M + (size_t)k * FDIM * FDIM;

    const int rg = lane >> 3;          // row within 8-row group (row&7 == rg)
    const int sc = (lane & 7) ^ rg;    // pre-swizzled source 16B-column

    f32x4 acc0[4][4] = {};             // P over i in [0,128)
    f32x4 acc1[4][4] = {};             // P over i in [128,256)

    auto stageF = [&](int buf, int c) {
        #pragma unroll
        for (int q = 0; q < 4; q++) {
            int g = wid * 4 + q;
            const short* src = F + ((size_t)(sbase + g * 8 + rg)) * FDIM + c * 64 + sc * 8;
            __builtin_amdgcn_global_load_lds((const unsigned*)src,
                                             (unsigned*)&Ft[buf][g * 512], 16, 0, 0);
        }
    };
    auto stageW = [&](int buf, int ihrow, int c) {
        #pragma unroll
        for (int q = 0; q < 4; q++) {
            int g = wid * 4 + q;
            const short* src = Mk + ((size_t)(ihrow * 128 + g * 8 + rg)) * FDIM + c * 64 + sc * 8;
            __builtin_amdgcn_global_load_lds((const unsigned*)src,
                                             (unsigned*)&Mt[buf][g * 512], 16, 0, 0);
        }
    };

    const int rlow = lane & 15, kq = lane >> 4;

    auto compute = [&](int fbuf, int mbuf, f32x4 (&acc)[4][4]) {
        bf16x8 afr[4][2], bfr[4][2];
        #pragma unroll
        for (int m = 0; m < 4; m++) {
            int row = wm * 64 + m * 16 + rlow;
            #pragma unroll
            for (int kk = 0; kk < 2; kk++) {
                int c16 = (kk * 4 + kq) ^ (row & 7);
                afr[m][kk] = *(const bf16x8*)&Ft[fbuf][row * 64 + c16 * 8];
            }
        }
        #pragma unroll
        for (int n = 0; n < 4; n++) {
            int row = wn * 64 + n * 16 + rlow;
            #pragma unroll
            for (int kk = 0; kk < 2; kk++) {
                int c16 = (kk * 4 + kq) ^ (row & 7);
                bfr[n][kk] = *(const bf16x8*)&Mt[mbuf][row * 64 + c16 * 8];
            }
        }
        #pragma unroll
        for (int m = 0; m < 4; m++)
            #pragma unroll
            for (int n = 0; n < 4; n++)
                #pragma unroll
                for (int kk = 0; kk < 2; kk++)
                    acc[m][n] = __builtin_amdgcn_mfma_f32_16x16x32_bf16(
                        afr[m][kk], bfr[n][kk], acc[m][n], 0, 0, 0);
    };

    // steps: s0(ih0,c0,F0,M0) s1(ih1,c0,F0,M1) s2(ih0,c1,F1,M0)
    //        s3(ih1,c1,F1,M1) s4(ih1,c2,F0,M0) s5(ih1,c3,F1,M1)
    stageF(0, 0); stageW(0, 0, 0);
    stageW(1, 1, 0);                   // step1 W
    __syncthreads();
    compute(0, 0, acc0);               // step0
    __syncthreads();
    stageF(1, 1); stageW(0, 0, 1);     // step2 operands
    __syncthreads();
    compute(0, 1, acc1);               // step1
    __syncthreads();
    stageW(1, 1, 1);                   // step3 W
    __syncthreads();
    compute(1, 0, acc0);               // step2
    __syncthreads();
    stageF(0, 2); stageW(0, 1, 2);     // step4 operands (Ft0 free: last read step1)
    __syncthreads();
    compute(1, 1, acc1);               // step3
    __syncthreads();
    stageF(1, 3); stageW(1, 1, 3);     // step5 operands (Ft1/Mt1 free: last read step3)
    __syncthreads();
    compute(0, 0, acc1);               // step4
    __syncthreads();
    compute(1, 1, acc1);               // step5

    // ---- epilogue: psum[s] = sum over BOTH i-halves of F[s,i]*P[s,i]
    float psum[4][4];
    #pragma unroll
    for (int m = 0; m < 4; m++) {
        #pragma unroll
        for (int q = 0; q < 4; q++) {
            int srow = wm * 64 + m * 16 + kq * 4 + q;
            const short* fr0 = F + (size_t)(sbase + srow) * FDIM + wn * 64 + rlow;
            float p = 0.0f;
            #pragma unroll
            for (int n = 0; n < 4; n++)
                p += bf2f(fr0[n * 16]) * acc0[m][n][q];
            #pragma unroll
            for (int n = 0; n < 4; n++)
                p += bf2f(fr0[128 + n * 16]) * acc1[m][n][q];
            psum[m][q] = p;
        }
    }
    #pragma unroll
    for (int off = 1; off < 16; off <<= 1)
        #pragma unroll
        for (int m = 0; m < 4; m++)
            #pragma unroll
            for (int q = 0; q < 4; q++)
                psum[m][q] += __shfl_xor(psum[m][q], off, 64);

    if (rlow == 0) {
        #pragma unroll
        for (int m = 0; m < 4; m++)
            #pragma unroll
            for (int q = 0; q < 4; q++) {
                int srow = wm * 64 + m * 16 + kq * 4 + q;
                lp2[((size_t)wn * KMIX + k) * STOT + sbase + srow] = psum[m][q];
            }
    }
}

// ---------------------------------------------------------------------------
// reduce (r10-verbatim): logsumexp + softplus + block partials; LAST block
// (device-scope ticket) sums the 32 partials in fixed order and writes J.
// ---------------------------------------------------------------------------
__global__ void reduce_kernel(const float* __restrict__ lp2,
                              const float* __restrict__ logc,
                              float* __restrict__ partials,
                              unsigned* __restrict__ counter,
                              float* __restrict__ out) {
    const int t = threadIdx.x;
    const int s = blockIdx.x * 256 + t;

    float v[KMIX];
    #pragma unroll
    for (int k = 0; k < KMIX; k++) {
        v[k] = lp2[((size_t)0 * KMIX + k) * STOT + s]
             + lp2[((size_t)1 * KMIX + k) * STOT + s]
             + logc[k];
    }
    float mx = v[0];
    #pragma unroll
    for (int k = 1; k < KMIX; k++) mx = fmaxf(mx, v[k]);
    float sum = 0.0f;
    #pragma unroll
    for (int k = 0; k < KMIX; k++) sum += expf(v[k] - mx);
    const float lp = mx + logf(sum);

    // n == m -> term1 = -softplus(-lp_data), term2 = -softplus(lp_noise)
    const float term = (s < NSAMP) ? -softplusf(-lp) : -softplusf(lp);

    float bsum = term;
    #pragma unroll
    for (int off = 32; off; off >>= 1) bsum += __shfl_down(bsum, off);
    __shared__ float wsum[4];
    if ((t & 63) == 0) wsum[t >> 6] = bsum;
    __syncthreads();

    if (t == 0) {
        partials[blockIdx.x] = wsum[0] + wsum[1] + wsum[2] + wsum[3];
        __threadfence();                              // release partial
        unsigned old = atomicAdd(counter, 1u);        // device-scope ticket
        if (old == 31u) {                             // last block: finalize
            __threadfence();                          // acquire all partials
            float tot = 0.0f;
            #pragma unroll
            for (int b = 0; b < 32; b++) tot += partials[b];
            out[0] = tot * (1.0f / (float)NSAMP);
        }
    }
}

// ---------------------------------------------------------------------------
extern "C" void kernel_launch(void* const* d_in, const int* in_sizes, int n_in,
                              void* d_out, int out_size, void* d_ws, size_t ws_size,
                              hipStream_t stream) {
    (void)in_sizes; (void)n_in; (void)out_size; (void)ws_size;
    const float* X     = (const float*)d_in[0];
    const float* noise = (const float*)d_in[1];
    const float* theta = (const float*)d_in[2];
    const float* logc  = (const float*)d_in[3];
    float* out = (float*)d_out;
    float* ws  = (float*)d_ws;

    short*    Fb    = (short*)(ws + OF_F);
    short*    Wb    = (short*)(ws + OF_M);
    float*    lp2   = ws + OF_LP4;
    float*    parts = ws + OF_PT;
    unsigned* ctr   = (unsigned*)(ws + OF_CT);

    prep_kernel<<<FEAT_BLOCKS + WB_BLOCKS, 256, 0, stream>>>(X, noise, theta, Fb, Wb, ctr);
    gemm_fused<<<KMIX * (STOT / 128), 256, 0, stream>>>(Fb, Wb, lp2);
    reduce_kernel<<<STOT / 256, 256, 0, stream>>>(lp2, logc, parts, ctr, out);
}